// Round 1
// baseline (3904.448 us; speedup 1.0000x reference)
//
#include <hip/hip_runtime.h>
#include <hip/hip_bf16.h>

#define BATCH 512
#define TSTEPS 64
#define DIN 1024
#define HID 512
#define G3 1536
#define MROWS (BATCH * TSTEPS)
#define POUT 512  // WIN*COUT

// ---------------------------------------------------------------------------
// Kernel 1: xg = X @ W_in + b_in   (M=32768, K=1024, N=1536), fp32 -> bf16 out
// Classic 64x64 tile, BK=16, 256 threads, 4x4 register micro-tile.
// ---------------------------------------------------------------------------
__global__ __launch_bounds__(256) void gemm_xg(const float* __restrict__ X,
                                               const float* __restrict__ W,
                                               const float* __restrict__ bin,
                                               __hip_bfloat16* __restrict__ XG) {
  __shared__ __align__(16) float As[16][68];  // [k][m], padded
  __shared__ __align__(16) float Bs[16][68];  // [k][n], padded
  const int tid = threadIdx.x;
  const int tx = tid & 15, ty = tid >> 4;
  const int row0 = blockIdx.x * 64, col0 = blockIdx.y * 64;
  float acc[4][4] = {};
  for (int k0 = 0; k0 < DIN; k0 += 16) {
    {  // A tile: 64 rows x 16 k, one float4 per thread, store transposed
      const int r = tid >> 2, c = (tid & 3) << 2;
      const float4 a = *reinterpret_cast<const float4*>(
          &X[(size_t)(row0 + r) * DIN + k0 + c]);
      As[c + 0][r] = a.x; As[c + 1][r] = a.y;
      As[c + 2][r] = a.z; As[c + 3][r] = a.w;
    }
    {  // B tile: 16 k-rows x 64 cols, one float4 per thread
      const int r = tid >> 4, c = (tid & 15) << 2;
      *reinterpret_cast<float4*>(&Bs[r][c]) =
          *reinterpret_cast<const float4*>(&W[(size_t)(k0 + r) * G3 + col0 + c]);
    }
    __syncthreads();
#pragma unroll
    for (int kk = 0; kk < 16; ++kk) {
      const float4 a = *reinterpret_cast<const float4*>(&As[kk][ty << 2]);
      const float4 b = *reinterpret_cast<const float4*>(&Bs[kk][tx << 2]);
      const float av[4] = {a.x, a.y, a.z, a.w};
      const float bv[4] = {b.x, b.y, b.z, b.w};
#pragma unroll
      for (int i = 0; i < 4; ++i)
#pragma unroll
        for (int j = 0; j < 4; ++j)
          acc[i][j] = fmaf(av[i], bv[j], acc[i][j]);
    }
    __syncthreads();
  }
#pragma unroll
  for (int i = 0; i < 4; ++i) {
    const int m = row0 + (ty << 2) + i;
#pragma unroll
    for (int j = 0; j < 4; ++j) {
      const int n = col0 + (tx << 2) + j;
      XG[(size_t)m * G3 + n] = __float2bfloat16(acc[i][j] + bin[n]);
    }
  }
}

// ---------------------------------------------------------------------------
// Kernel 2: GRU scan. 128 blocks x 4 batches each; recurrence is
// batch-independent so no grid sync is needed. h kept transposed in LDS
// ([k][4] -> one ds_read_b128 broadcast per k). U streamed from L2.
// ---------------------------------------------------------------------------
__global__ __launch_bounds__(256) void gru_scan(const __hip_bfloat16* __restrict__ XG,
                                                const float* __restrict__ U,
                                                const float* __restrict__ brec,
                                                float* __restrict__ HT) {
  __shared__ __align__(16) float hS[HID][4];  // [k][batch] transposed, 8 KB
  __shared__ float hgS[4][G3];                // 24 KB
  const int tid = threadIdx.x;
  const int b0 = blockIdx.x << 2;

  for (int i = tid; i < HID * 4; i += 256)
    reinterpret_cast<float*>(hS)[i] = 0.f;
  float bR[6];
#pragma unroll
  for (int i = 0; i < 6; ++i) bR[i] = brec[tid + (i << 8)];
  __syncthreads();

  for (int t = 0; t < TSTEPS; ++t) {
    // ---- hg = h @ U + b_rec : each thread owns 6 of the 1536 gate cols ----
    float acc[6][4];
#pragma unroll
    for (int i = 0; i < 6; ++i)
#pragma unroll
      for (int bb = 0; bb < 4; ++bb) acc[i][bb] = bR[i];
    for (int k = 0; k < HID; ++k) {
      const float4 h4 = *reinterpret_cast<const float4*>(&hS[k][0]);
      const float* Uk = &U[(size_t)k * G3 + tid];
#pragma unroll
      for (int i = 0; i < 6; ++i) {
        const float u = Uk[i << 8];
        acc[i][0] = fmaf(h4.x, u, acc[i][0]);
        acc[i][1] = fmaf(h4.y, u, acc[i][1]);
        acc[i][2] = fmaf(h4.z, u, acc[i][2]);
        acc[i][3] = fmaf(h4.w, u, acc[i][3]);
      }
    }
#pragma unroll
    for (int i = 0; i < 6; ++i) {
      const int j = tid + (i << 8);
#pragma unroll
      for (int bb = 0; bb < 4; ++bb) hgS[bb][j] = acc[i][bb];
    }
    __syncthreads();

    // ---- gates + state update ----
#pragma unroll
    for (int ii = 0; ii < 2; ++ii) {
      const int j = tid + (ii << 8);
#pragma unroll
      for (int bb = 0; bb < 4; ++bb) {
        const size_t bt = (size_t)(b0 + bb) * TSTEPS + t;
        const __hip_bfloat16* xr = &XG[bt * G3];
        const float xz = __bfloat162float(xr[j]);
        const float xrr = __bfloat162float(xr[j + 512]);
        const float xh = __bfloat162float(xr[j + 1024]);
        const float hz = hgS[bb][j];
        const float hr = hgS[bb][j + 512];
        const float hh = hgS[bb][j + 1024];
        const float z = 1.f / (1.f + __expf(-(xz + hz)));
        const float r = 1.f / (1.f + __expf(-(xrr + hr)));
        const float hc = fmaxf(fmaf(r, hh, xh), 0.f);
        // h_new = z*h + (1-z)*hc  ==  hc + z*(h - hc)
        hS[j][bb] = fmaf(z, hS[j][bb] - hc, hc);
      }
    }
    __syncthreads();
  }

  for (int i = tid; i < 4 * HID; i += 256) {
    const int bb = i >> 9, j = i & 511;
    HT[(size_t)(b0 + bb) * HID + j] = hS[j][bb];
  }
}

// ---------------------------------------------------------------------------
// Kernel 3: out[b][p] = sum_k hT[b][k] * (W2[k][p] + W2[k+512][p]) + b2[p]
// (cat(h,h) @ W2 == h @ (W2_top + W2_bot))
// ---------------------------------------------------------------------------
__global__ __launch_bounds__(256) void final_proj(const float* __restrict__ HT,
                                                  const float* __restrict__ W2,
                                                  const float* __restrict__ b2,
                                                  float* __restrict__ OUT) {
  const int b = blockIdx.x >> 1;
  const int p = ((blockIdx.x & 1) << 8) + threadIdx.x;
  float acc = b2[p];
  const float* h = &HT[(size_t)b * HID];
  for (int k = 0; k < HID; ++k) {
    acc = fmaf(h[k], W2[(size_t)k * POUT + p] + W2[(size_t)(k + HID) * POUT + p],
               acc);
  }
  OUT[(size_t)b * POUT + p] = acc;
}

// ---------------------------------------------------------------------------
extern "C" void kernel_launch(void* const* d_in, const int* in_sizes, int n_in,
                              void* d_out, int out_size, void* d_ws,
                              size_t ws_size, hipStream_t stream) {
  const float* X    = (const float*)d_in[0];
  const float* Win  = (const float*)d_in[1];
  const float* bin  = (const float*)d_in[2];
  const float* U    = (const float*)d_in[3];
  const float* brec = (const float*)d_in[4];
  const float* W2   = (const float*)d_in[5];
  const float* b2   = (const float*)d_in[6];
  float* OUT = (float*)d_out;

  // workspace: xg bf16 [32768][1536] (100.7 MB), then hT fp32 [512][512] (1 MB)
  __hip_bfloat16* XG = (__hip_bfloat16*)d_ws;
  float* HT = (float*)((char*)d_ws + (size_t)MROWS * G3 * sizeof(__hip_bfloat16));

  gemm_xg<<<dim3(MROWS / 64, G3 / 64), 256, 0, stream>>>(X, Win, bin, XG);
  gru_scan<<<dim3(BATCH / 4), 256, 0, stream>>>(XG, U, brec, HT);
  final_proj<<<dim3((BATCH * POUT) / 256), 256, 0, stream>>>(HT, W2, b2, OUT);
}

// Round 2
// 3671.141 us; speedup vs baseline: 1.0636x; 1.0636x over previous
//
#include <hip/hip_runtime.h>
#include <hip/hip_bf16.h>
#include <stdint.h>

#define BATCH 512
#define TSTEPS 64
#define DIN 1024
#define HID 512
#define G3 1536
#define MROWS (BATCH * TSTEPS)
#define POUT 512

typedef __attribute__((ext_vector_type(8))) short bf16x8;
typedef __attribute__((ext_vector_type(4))) float f32x4;

__device__ __forceinline__ float bf2f(short s) {
  union { unsigned u; float f; } v;
  v.u = ((unsigned)(unsigned short)s) << 16;
  return v.f;
}
__device__ __forceinline__ short f2bf(float f) {
  __hip_bfloat16 h = __float2bfloat16(f);
  short s;
  __builtin_memcpy(&s, &h, 2);
  return s;
}
__device__ __forceinline__ void gload_lds16(const void* g, void* l) {
  __builtin_amdgcn_global_load_lds(
      (const __attribute__((address_space(1))) void*)g,
      (__attribute__((address_space(3))) void*)l, 16, 0, 0);
}

// ---------------------------------------------------------------------------
// transpose + fp32->bf16 cast: out[c][r] = bf16(in[r][c]); R,C multiples of 32
// ---------------------------------------------------------------------------
__global__ __launch_bounds__(256) void transpose_cast(const float* __restrict__ in,
                                                      short* __restrict__ out,
                                                      int R, int C) {
  __shared__ float tile[32][33];
  const int c0 = blockIdx.x * 32, r0 = blockIdx.y * 32;
  const int tx = threadIdx.x & 31, ty = threadIdx.x >> 5;  // ty 0..7
#pragma unroll
  for (int i = 0; i < 4; ++i) {
    const int r = r0 + ty + i * 8;
    tile[ty + i * 8][tx] = in[(size_t)r * C + c0 + tx];
  }
  __syncthreads();
#pragma unroll
  for (int i = 0; i < 4; ++i) {
    const int c = c0 + ty + i * 8;
    out[(size_t)c * R + r0 + tx] = f2bf(tile[tx][ty + i * 8]);
  }
}

// ---------------------------------------------------------------------------
// Kernel 1: XG = bf16(X @ W_in + b_in). MFMA bf16, 128x128 tile, BK=64.
// A (X fp32) reg-staged with swizzled ds_write; B (Wt bf16 [n][k]) via
// global_load_lds w/ pre-swizzled source. Swizzle: chunk ^= (row&7).
// ---------------------------------------------------------------------------
__global__ __launch_bounds__(256) void gemm_xg_mfma(const float* __restrict__ X,
                                                    const short* __restrict__ Wt,
                                                    const float* __restrict__ bin,
                                                    __hip_bfloat16* __restrict__ XG) {
  __shared__ __align__(16) short As[128 * 64];  // [m][k], chunk-swizzled
  __shared__ __align__(16) short Bs[128 * 64];  // [n][k], chunk-swizzled
  const int tid = threadIdx.x;
  const int w = tid >> 6, l = tid & 63;
  const int lc = l & 15, lg = l >> 4;

  // XCD-aware swizzle (3072 % 8 == 0 -> bijective)
  const int nwg = gridDim.x;
  const int wg = (blockIdx.x & 7) * (nwg >> 3) + (blockIdx.x >> 3);
  const int rt = wg & 255, ct = wg >> 8;  // 256 x 12
  const int row0 = rt * 128, col0 = ct * 128;

  const int wm = w >> 1, wn = w & 1;  // 2x2 wave grid, 64x64 per wave

  f32x4 acc[4][4];
#pragma unroll
  for (int mt = 0; mt < 4; ++mt)
#pragma unroll
    for (int nt = 0; nt < 4; ++nt) acc[mt][nt] = (f32x4){0.f, 0.f, 0.f, 0.f};

  const int tr = tid >> 3, p = tid & 7;

  for (int k0 = 0; k0 < DIN; k0 += 64) {
    // A: global fp32 -> regs (issue early, overlaps prev compute)
    float4 ar[4][2];
#pragma unroll
    for (int i = 0; i < 4; ++i) {
      const int r = i * 32 + tr;
      const int s = p ^ (r & 7);
      const float* xp = &X[(size_t)(row0 + r) * DIN + k0 + s * 8];
      ar[i][0] = *reinterpret_cast<const float4*>(xp);
      ar[i][1] = *reinterpret_cast<const float4*>(xp + 4);
    }
    __syncthreads();  // prev compute done reading LDS
    // A: regs -> LDS (swizzled slot = phys chunk p)
#pragma unroll
    for (int i = 0; i < 4; ++i) {
      const int r = i * 32 + tr;
      bf16x8 v;
      v[0] = f2bf(ar[i][0].x); v[1] = f2bf(ar[i][0].y);
      v[2] = f2bf(ar[i][0].z); v[3] = f2bf(ar[i][0].w);
      v[4] = f2bf(ar[i][1].x); v[5] = f2bf(ar[i][1].y);
      v[6] = f2bf(ar[i][1].z); v[7] = f2bf(ar[i][1].w);
      *reinterpret_cast<bf16x8*>((char*)As + r * 128 + p * 16) = v;
    }
    // B: global_load_lds, linear LDS dest + pre-swizzled global source
#pragma unroll
    for (int i = 0; i < 4; ++i) {
      const int rr = w * 32 + i * 8 + (l >> 3);
      const int pp = l & 7;
      const int s = pp ^ (rr & 7);
      gload_lds16(&Wt[(size_t)(col0 + rr) * DIN + k0 + s * 8],
                  (char*)Bs + (w * 32 + i * 8) * 128);
    }
    __syncthreads();  // staging visible
#pragma unroll
    for (int kc = 0; kc < 2; ++kc) {
      bf16x8 a[4], b[4];
#pragma unroll
      for (int mt = 0; mt < 4; ++mt) {
        const int R = wm * 64 + mt * 16 + lc;
        const int ch = (kc * 4 + lg) ^ (R & 7);
        a[mt] = *reinterpret_cast<const bf16x8*>((const char*)As + R * 128 + ch * 16);
      }
#pragma unroll
      for (int nt = 0; nt < 4; ++nt) {
        const int Rn = wn * 64 + nt * 16 + lc;
        const int ch = (kc * 4 + lg) ^ (Rn & 7);
        b[nt] = *reinterpret_cast<const bf16x8*>((const char*)Bs + Rn * 128 + ch * 16);
      }
#pragma unroll
      for (int mt = 0; mt < 4; ++mt)
#pragma unroll
        for (int nt = 0; nt < 4; ++nt)
          acc[mt][nt] = __builtin_amdgcn_mfma_f32_16x16x32_bf16(a[mt], b[nt],
                                                                acc[mt][nt], 0, 0, 0);
    }
  }

  // epilogue: + bias, bf16 store. C/D: col = lane&15, row = (lane>>4)*4 + reg
  float bv[4];
#pragma unroll
  for (int nt = 0; nt < 4; ++nt) bv[nt] = bin[col0 + wn * 64 + nt * 16 + lc];
#pragma unroll
  for (int mt = 0; mt < 4; ++mt) {
#pragma unroll
    for (int nt = 0; nt < 4; ++nt) {
      const int col = col0 + wn * 64 + nt * 16 + lc;
#pragma unroll
      for (int rr = 0; rr < 4; ++rr) {
        const int row = row0 + wm * 64 + mt * 16 + lg * 4 + rr;
        XG[(size_t)row * G3 + col] = __float2bfloat16(acc[mt][nt][rr] + bv[nt]);
      }
    }
  }
}

// ---------------------------------------------------------------------------
// Kernel 2: GRU scan, MFMA. 32 blocks x 512 threads (8 waves), 16 batches
// each. h bf16 in LDS [16][520] (pad -> 2-way bank aliasing = free). Wave w
// owns gate columns {g*512 + w*64 .. +63} so z/r/hh for a given h-column live
// in the SAME lane's accumulators -> gates fully in-register.
// ---------------------------------------------------------------------------
__global__ __launch_bounds__(512, 2) void gru_scan_mfma(
    const __hip_bfloat16* __restrict__ XG, const short* __restrict__ Ut,
    const float* __restrict__ brec, float* __restrict__ HT) {
  __shared__ __align__(16) short hS[16 * 520];
  const int tid = threadIdx.x, w = tid >> 6, l = tid & 63;
  const int b0 = blockIdx.x * 16;
  const int cw = w * 64;
  const int lc = l & 15, lg = l >> 4;

  for (int i = tid; i < 16 * 520; i += 512) hS[i] = 0;

  float br[3][4];
#pragma unroll
  for (int g = 0; g < 3; ++g)
#pragma unroll
    for (int t4 = 0; t4 < 4; ++t4) br[g][t4] = brec[g * 512 + cw + t4 * 16 + lc];
  __syncthreads();

  for (int t = 0; t < TSTEPS; ++t) {
    // phase A: A-frags (h) — all waves read all 16 batch rows
    bf16x8 af[16];
#pragma unroll
    for (int kc = 0; kc < 16; ++kc)
      af[kc] = *reinterpret_cast<const bf16x8*>((const char*)hS + lc * 1040 +
                                                kc * 64 + lg * 16);
    // prefetch xg for this step (independent of LDS)
    short xgs[3][4][4];
#pragma unroll
    for (int t4 = 0; t4 < 4; ++t4)
#pragma unroll
      for (int r = 0; r < 4; ++r) {
        const __hip_bfloat16* xp =
            XG + ((size_t)(b0 + lg * 4 + r) * TSTEPS + t) * G3 + cw + t4 * 16 + lc;
        xgs[0][t4][r] = *(const short*)(xp);
        xgs[1][t4][r] = *(const short*)(xp + 512);
        xgs[2][t4][r] = *(const short*)(xp + 1024);
      }
    __syncthreads();  // A-frags read before anyone rewrites h

    // phase B: hg = h @ U for this wave's 12 col-tiles, acc in registers
    f32x4 za[3][4];
#pragma unroll
    for (int g = 0; g < 3; ++g) {
#pragma unroll
      for (int t4 = 0; t4 < 4; ++t4) {
        const int col = g * 512 + cw + t4 * 16 + lc;
        const short* bp = Ut + (size_t)col * HID + lg * 8;
        f32x4 acc = (f32x4){0.f, 0.f, 0.f, 0.f};
#pragma unroll
        for (int kc = 0; kc < 16; ++kc) {
          const bf16x8 bf = *reinterpret_cast<const bf16x8*>(bp + kc * 32);
          acc = __builtin_amdgcn_mfma_f32_16x16x32_bf16(af[kc], bf, acc, 0, 0, 0);
        }
        za[g][t4] = acc;
      }
    }

    // phase C: gates in-register; lane holds rows lg*4+0..3 of col cw+t4*16+lc
#pragma unroll
    for (int t4 = 0; t4 < 4; ++t4) {
      const int j = cw + t4 * 16 + lc;
#pragma unroll
      for (int r = 0; r < 4; ++r) {
        const int R = lg * 4 + r;
        const float xz = bf2f(xgs[0][t4][r]);
        const float xr = bf2f(xgs[1][t4][r]);
        const float xh = bf2f(xgs[2][t4][r]);
        const float hz = za[0][t4][r] + br[0][t4];
        const float hr = za[1][t4][r] + br[1][t4];
        const float hh = za[2][t4][r] + br[2][t4];
        const float z = 1.f / (1.f + __expf(-(xz + hz)));
        const float rg = 1.f / (1.f + __expf(-(xr + hr)));
        const float hc = fmaxf(fmaf(rg, hh, xh), 0.f);
        const int hi = R * 520 + j;
        const float hold = bf2f(hS[hi]);
        hS[hi] = f2bf(fmaf(z, hold - hc, hc));
      }
    }
    __syncthreads();  // h update visible before next step's A-frags
  }

  for (int i = tid; i < 16 * HID; i += 512) {
    const int R = i >> 9, j = i & 511;
    HT[(size_t)(b0 + R) * HID + j] = bf2f(hS[R * 520 + j]);
  }
}

// ---------------------------------------------------------------------------
// Kernel 3: out = cat(hT,hT) @ W2 + b2 == hT @ (W2_top + W2_bot) + b2
// ---------------------------------------------------------------------------
__global__ __launch_bounds__(256) void final_proj(const float* __restrict__ HT,
                                                  const float* __restrict__ W2,
                                                  const float* __restrict__ b2,
                                                  float* __restrict__ OUT) {
  const int b = blockIdx.x >> 1;
  const int pp = ((blockIdx.x & 1) << 8) + threadIdx.x;
  float acc = b2[pp];
  const float* h = &HT[(size_t)b * HID];
  for (int k = 0; k < HID; ++k)
    acc = fmaf(h[k], W2[(size_t)k * POUT + pp] + W2[(size_t)(k + HID) * POUT + pp], acc);
  OUT[(size_t)b * POUT + pp] = acc;
}

// ---------------------------------------------------------------------------
extern "C" void kernel_launch(void* const* d_in, const int* in_sizes, int n_in,
                              void* d_out, int out_size, void* d_ws,
                              size_t ws_size, hipStream_t stream) {
  const float* X    = (const float*)d_in[0];
  const float* Win  = (const float*)d_in[1];
  const float* bin  = (const float*)d_in[2];
  const float* U    = (const float*)d_in[3];
  const float* brec = (const float*)d_in[4];
  const float* W2   = (const float*)d_in[5];
  const float* b2   = (const float*)d_in[6];
  float* OUT = (float*)d_out;

  char* ws = (char*)d_ws;
  __hip_bfloat16* XG = (__hip_bfloat16*)ws;                       // 100,663,296 B
  short* Wt = (short*)(ws + (size_t)MROWS * G3 * 2);              //   3,145,728 B
  short* Ut = (short*)(ws + (size_t)MROWS * G3 * 2 + (size_t)G3 * DIN * 2);  // 1,572,864 B
  float* HT = (float*)(ws + (size_t)MROWS * G3 * 2 + (size_t)G3 * DIN * 2 +
                       (size_t)G3 * HID * 2);                     //   1,048,576 B

  transpose_cast<<<dim3(G3 / 32, DIN / 32), 256, 0, stream>>>(Win, Wt, DIN, G3);
  transpose_cast<<<dim3(G3 / 32, HID / 32), 256, 0, stream>>>(U, Ut, HID, G3);
  gemm_xg_mfma<<<(MROWS / 128) * (G3 / 128), 256, 0, stream>>>(X, Wt, bin, XG);
  gru_scan_mfma<<<BATCH / 16, 512, 0, stream>>>(XG, Ut, brec, HT);
  final_proj<<<(BATCH * POUT) / 256, 256, 0, stream>>>(HT, W2, b2, OUT);
}